// Round 4
// baseline (4935.584 us; speedup 1.0000x reference)
//
#include <hip/hip_runtime.h>
#include <math.h>

#define SEQLEN 1024
#define DIM 512
#define MM 512

typedef float f32x4 __attribute__((ext_vector_type(4)));

__device__ __forceinline__ float sigf(float x) {
  return __builtin_amdgcn_rcpf(1.0f + __expf(-x));
}
__device__ __forceinline__ float tanhfast(float x) {
  return 1.0f - 2.0f * __builtin_amdgcn_rcpf(1.0f + __expf(2.0f * x));
}

// ---------------- K1: Gx[seq][t][g] = emb[ids[t]] . Wxcat[g] + bias_cat[g] ----------------
// Wxcat rows: [Wioux (1536 rows); Wfx (512 rows)], 512 cols.  Gx: [2][1024][2048]
__global__ __launch_bounds__(256) void gx_gemm(
    const int* __restrict__ l_ids, const int* __restrict__ r_ids,
    const float* __restrict__ emb,
    const float* __restrict__ Wioux, const float* __restrict__ Wfx,
    const float* __restrict__ bioux, const float* __restrict__ biouh,
    const float* __restrict__ bfx, const float* __restrict__ bfh,
    float* __restrict__ gx)
{
  __shared__ __align__(16) float At[32][68];   // transposed tiles: [k][row]
  __shared__ __align__(16) float Bt[32][68];
  const int tid = threadIdx.x;
  const int bid = blockIdx.x;
  const int seq = bid >> 9;            // 2
  const int tt  = (bid >> 5) & 15;     // 16 t-tiles of 64
  const int gt  = bid & 31;            // 32 g-tiles of 64
  const int t0 = tt * 64, g0 = gt * 64;
  const int* ids = seq ? r_ids : l_ids;

  const int li = tid >> 2;             // 0..63 (tile row)
  const int lk = (tid & 3) * 8;        // k chunk
  const float* arow = emb + (size_t)ids[t0 + li] * DIM;
  const int gg = g0 + li;
  const float* brow = (gg < 1536) ? (Wioux + (size_t)gg * DIM)
                                  : (Wfx + (size_t)(gg - 1536) * DIM);
  const int tr = tid >> 4;             // 0..15 micro-row group
  const int tc = tid & 15;             // 0..15 micro-col group

  float acc[4][4];
  #pragma unroll
  for (int i = 0; i < 4; ++i) { acc[i][0]=0.f; acc[i][1]=0.f; acc[i][2]=0.f; acc[i][3]=0.f; }

  for (int kb = 0; kb < 16; ++kb) {
    const int k0 = kb * 32;
    float4 av0 = *(const float4*)(arow + k0 + lk);
    float4 av1 = *(const float4*)(arow + k0 + lk + 4);
    float4 bv0 = *(const float4*)(brow + k0 + lk);
    float4 bv1 = *(const float4*)(brow + k0 + lk + 4);
    __syncthreads();
    At[lk+0][li]=av0.x; At[lk+1][li]=av0.y; At[lk+2][li]=av0.z; At[lk+3][li]=av0.w;
    At[lk+4][li]=av1.x; At[lk+5][li]=av1.y; At[lk+6][li]=av1.z; At[lk+7][li]=av1.w;
    Bt[lk+0][li]=bv0.x; Bt[lk+1][li]=bv0.y; Bt[lk+2][li]=bv0.z; Bt[lk+3][li]=bv0.w;
    Bt[lk+4][li]=bv1.x; Bt[lk+5][li]=bv1.y; Bt[lk+6][li]=bv1.z; Bt[lk+7][li]=bv1.w;
    __syncthreads();
    #pragma unroll
    for (int k = 0; k < 32; ++k) {
      float4 a4 = *(const float4*)&At[k][tr*4];
      float4 b4 = *(const float4*)&Bt[k][tc*4];
      acc[0][0]+=a4.x*b4.x; acc[0][1]+=a4.x*b4.y; acc[0][2]+=a4.x*b4.z; acc[0][3]+=a4.x*b4.w;
      acc[1][0]+=a4.y*b4.x; acc[1][1]+=a4.y*b4.y; acc[1][2]+=a4.y*b4.z; acc[1][3]+=a4.y*b4.w;
      acc[2][0]+=a4.z*b4.x; acc[2][1]+=a4.z*b4.y; acc[2][2]+=a4.z*b4.z; acc[2][3]+=a4.z*b4.w;
      acc[3][0]+=a4.w*b4.x; acc[3][1]+=a4.w*b4.y; acc[3][2]+=a4.w*b4.z; acc[3][3]+=a4.w*b4.w;
    }
  }
  const int gc = g0 + tc * 4;
  float badd[4];
  #pragma unroll
  for (int jj = 0; jj < 4; ++jj) {
    int g = gc + jj;
    badd[jj] = (g < 1536) ? (bioux[g] + biouh[g]) : (bfx[g-1536] + bfh[g-1536]);
  }
  #pragma unroll
  for (int ii = 0; ii < 4; ++ii) {
    float4 r;
    r.x = acc[ii][0] + badd[0];
    r.y = acc[ii][1] + badd[1];
    r.z = acc[ii][2] + badd[2];
    r.w = acc[ii][3] + badd[3];
    size_t off = ((size_t)seq * SEQLEN + (size_t)(t0 + tr*4 + ii)) * 2048 + gc;
    *(float4*)(gx + off) = r;
  }
}

// ---------------- K2: persistent scan, 64 WGs, barrier-free, weights resident -------------
// hbuf: [2 parity][512 j][4] = {h_l, tag, h_r, tag}; 16B atomic coherent stores.
// Thread (jl=tid>>5, g=(tid>>4)&1, b=tid&15): gate-rows {2g,2g+1} of j=wg*8+jl,
// cols [b*32,b*32+32) -> 64 weight floats/thread (register resident; ~190 VGPR total).
// Each WAVE privately stages all 512 h entries (8/lane) -> no __syncthreads in the loop.
__global__ __launch_bounds__(256, 1) void lstm_scan(
    const float* __restrict__ Wiouh, const float* __restrict__ Wfh,
    const float* __restrict__ gx,
    float* __restrict__ hbuf,       // zeroed by memset (tags start at 0)
    float* __restrict__ hB)         // [2 seq][512]
{
  const int tid  = threadIdx.x;
  const int wg   = blockIdx.x;      // 0..63
  const int b    = tid & 15;
  const int g    = (tid >> 4) & 1;
  const int jl   = tid >> 5;        // 0..7
  const int j    = wg * 8 + jl;
  const int lane = tid & 63;
  const int wv   = tid >> 6;        // wave id 0..3
  const bool owner = (b == 0) && (g == 0);

  // weights: gates {2g, 2g+1} of row j (gate order i,o,u,f), cols b*32..b*32+31
  float w0[32], w1[32];
  {
    const int g0r = 2 * g, g1r = 2 * g + 1;
    const float* r0 = (g0r < 3) ? (Wiouh + ((size_t)g0r * 512 + j) * MM)
                                : (Wfh + (size_t)j * MM);
    const float* r1 = (g1r < 3) ? (Wiouh + ((size_t)g1r * 512 + j) * MM)
                                : (Wfh + (size_t)j * MM);
    #pragma unroll
    for (int q = 0; q < 8; ++q) {
      f32x4 v0 = *(const f32x4*)(r0 + b * 32 + q * 4);
      f32x4 v1 = *(const f32x4*)(r1 + b * 32 + q * 4);
      w0[q*4+0]=v0[0]; w0[q*4+1]=v0[1]; w0[q*4+2]=v0[2]; w0[q*4+3]=v0[3];
      w1[q*4+0]=v1[0]; w1[q*4+1]=v1[1]; w1[q*4+2]=v1[2]; w1[q*4+3]=v1[3];
    }
  }

  // wave-private h staging: 4 waves x 16 chunks x (64 data + 4 pad) floats
  __shared__ __align__(16) float hsm[4 * 16 * 68];

  float cl = 0.0f, cr = 0.0f;       // persistent c state (owner lanes)

  for (int t = 0; t < SEQLEN; ++t) {
    // ---- gx prefetch (owner only) — hidden under the first poll round ----
    float gl[4], gr[4];
    if (owner) {
      #pragma unroll
      for (int r = 0; r < 4; ++r) {
        gl[r] = gx[(size_t)t * 2048 + r * 512 + j];
        gr[r] = gx[((size_t)SEQLEN + t) * 2048 + r * 512 + j];
      }
    }

    // ---- poll: 8 entries/lane (whole wave covers all 512), tight spin ----
    const float* pp = hbuf + (size_t)((t & 1) * 512 + lane * 8) * 4;
    const float tf = (float)t;
    f32x4 e0, e1, e2, e3, e4, e5, e6, e7;
    for (;;) {
      asm volatile(
        "global_load_dwordx4 %0, %8, off sc0 sc1\n\t"
        "global_load_dwordx4 %1, %8, off offset:16 sc0 sc1\n\t"
        "global_load_dwordx4 %2, %8, off offset:32 sc0 sc1\n\t"
        "global_load_dwordx4 %3, %8, off offset:48 sc0 sc1\n\t"
        "global_load_dwordx4 %4, %8, off offset:64 sc0 sc1\n\t"
        "global_load_dwordx4 %5, %8, off offset:80 sc0 sc1\n\t"
        "global_load_dwordx4 %6, %8, off offset:96 sc0 sc1\n\t"
        "global_load_dwordx4 %7, %8, off offset:112 sc0 sc1\n\t"
        "s_waitcnt vmcnt(0)"
        : "=&v"(e0), "=&v"(e1), "=&v"(e2), "=&v"(e3),
          "=&v"(e4), "=&v"(e5), "=&v"(e6), "=&v"(e7)
        : "v"(pp)
        : "memory");
      if (e0[1] >= tf && e1[1] >= tf && e2[1] >= tf && e3[1] >= tf &&
          e4[1] >= tf && e5[1] >= tf && e6[1] >= tf && e7[1] >= tf) break;
    }

    // ---- stage to wave-private LDS (no cross-wave sync needed) ----
    {
      float* hs = &hsm[wv * 1088 + (lane >> 2) * 68 + (lane & 3) * 16];
      f32x4 s0 = {e0[0], e0[2], e1[0], e1[2]};
      f32x4 s1 = {e2[0], e2[2], e3[0], e3[2]};
      f32x4 s2 = {e4[0], e4[2], e5[0], e5[2]};
      f32x4 s3 = {e6[0], e6[2], e7[0], e7[2]};
      ((f32x4*)hs)[0] = s0; ((f32x4*)hs)[1] = s1;
      ((f32x4*)hs)[2] = s2; ((f32x4*)hs)[3] = s3;
    }
    asm volatile("s_waitcnt lgkmcnt(0)" ::: "memory");
    __builtin_amdgcn_sched_barrier(0);

    // ---- LDS -> registers: this lane's 32 cols, both seqs ----
    float hl[32], hr[32];
    {
      const float* rb = &hsm[wv * 1088 + b * 68];
      #pragma unroll
      for (int q = 0; q < 16; ++q) {
        f32x4 v = *(const f32x4*)(rb + q * 4);
        hl[q*2+0] = v[0]; hr[q*2+0] = v[1];
        hl[q*2+1] = v[2]; hr[q*2+1] = v[3];
      }
    }

    // ---- GEMV partials: 2 gates x 2 seqs over 32 cols ----
    float a0l = 0.f, a1l = 0.f, a0r = 0.f, a1r = 0.f;
    #pragma unroll
    for (int k = 0; k < 32; ++k) {
      a0l += w0[k] * hl[k];
      a1l += w1[k] * hl[k];
      a0r += w0[k] * hr[k];
      a1r += w1[k] * hr[k];
    }
    #pragma unroll
    for (int m = 1; m < 16; m <<= 1) {
      a0l += __shfl_xor(a0l, m, 64);
      a1l += __shfl_xor(a1l, m, 64);
      a0r += __shfl_xor(a0r, m, 64);
      a1r += __shfl_xor(a1r, m, 64);
    }
    // cross-g merge: lane with g=0 fetches u/f sums from its g=1 partner (xor 16)
    const float b0l = __shfl_xor(a0l, 16, 64);
    const float b1l = __shfl_xor(a1l, 16, 64);
    const float b0r = __shfl_xor(a0r, 16, 64);
    const float b1r = __shfl_xor(a1r, 16, 64);

    // ---- owner: cell update + coherent 16B publish {h_l, tag, h_r, tag} ----
    if (owner) {
      const float il = a0l + gl[0], ol = a1l + gl[1], ul = b0l + gl[2], fl = b1l + gl[3];
      const float ir = a0r + gr[0], orr = a1r + gr[1], ur = b0r + gr[2], fr = b1r + gr[3];
      cl = sigf(il) * tanhfast(ul) + sigf(fl) * cl;
      cr = sigf(ir) * tanhfast(ur) + sigf(fr) * cr;
      const float h2l = sigf(ol) * tanhfast(cl);
      const float h2r = sigf(orr) * tanhfast(cr);
      const float tg = (float)(t + 1);
      f32x4 st; st[0] = h2l; st[1] = tg; st[2] = h2r; st[3] = tg;
      float* dp = hbuf + (size_t)((((t + 1) & 1) * 512 + j)) * 4;
      asm volatile("global_store_dwordx4 %0, %1, off sc0 sc1" :: "v"(dp), "v"(st) : "memory");
      if (t == SEQLEN - 1) {
        // hB = cell(x_last, 0, 0).h ; gate pre-acts are exactly gl/gr
        const float cBl = sigf(gl[0]) * tanhfast(gl[2]);
        const float cBr = sigf(gr[0]) * tanhfast(gr[2]);
        hB[j]       = sigf(gl[1]) * tanhfast(cBl);
        hB[512 + j] = sigf(gr[1]) * tanhfast(cBr);
      }
    }
  }
}

// ---------------- K3a: s = sigmoid(Wh @ vec + bh), 16 WGs x 16 rows ----------------
__global__ __launch_bounds__(256) void head1(
    const float* __restrict__ hbuf, const float* __restrict__ hB,
    const float* __restrict__ Wh, const float* __restrict__ bh,
    float* __restrict__ sv)
{
  __shared__ __align__(16) float vec[2048];
  const int tid = threadIdx.x;
  const int wg = blockIdx.x;  // 0..15
  // final h (tag 1024) lives at parity 0: entry j -> {h_l at j*4, h_r at j*4+2}
  for (int k = tid; k < 1024; k += 256) {
    float lv, rv;
    if (k < 512) { lv = hbuf[(size_t)k * 4]; rv = hbuf[(size_t)k * 4 + 2]; }
    else         { lv = hB[k - 512];         rv = hB[512 + (k - 512)]; }
    vec[k] = lv * rv;
    vec[1024 + k] = fabsf(lv - rv);
  }
  __syncthreads();
  const int row = wg * 16 + (tid >> 4);
  const int ln = tid & 15;
  const float* wr = Wh + (size_t)row * 2048 + ln * 128;
  const float* vp = vec + ln * 128;
  float acc = 0.0f;
  #pragma unroll
  for (int k = 0; k < 128; k += 4) {
    float4 wv = *(const float4*)(wr + k);
    float4 vv = *(const float4*)(vp + k);
    acc += wv.x*vv.x + wv.y*vv.y + wv.z*vv.z + wv.w*vv.w;
  }
  #pragma unroll
  for (int msk = 1; msk < 16; msk <<= 1) acc += __shfl_xor(acc, msk, 64);
  if (ln == 0) sv[row] = 1.0f / (1.0f + expf(-(acc + bh[row])));
}

// ---------------- K3b: logits = Wp @ s + bp ; log_softmax ----------------
__global__ __launch_bounds__(256) void head2(
    const float* __restrict__ sv, const float* __restrict__ Wp,
    const float* __restrict__ bp, float* __restrict__ out)
{
  __shared__ float s_l[256];
  __shared__ float lg[5];
  const int tid = threadIdx.x;
  s_l[tid] = sv[tid];
  __syncthreads();
  if (tid < 5) {
    float acc = bp[tid];
    for (int k = 0; k < 256; ++k) acc += Wp[tid*256 + k] * s_l[k];
    lg[tid] = acc;
  }
  __syncthreads();
  if (tid == 0) {
    float mx = lg[0];
    #pragma unroll
    for (int i = 1; i < 5; ++i) mx = fmaxf(mx, lg[i]);
    float sum = 0.0f;
    #pragma unroll
    for (int i = 0; i < 5; ++i) sum += expf(lg[i] - mx);
    const float lse = mx + logf(sum);
    #pragma unroll
    for (int i = 0; i < 5; ++i) out[i] = lg[i] - lse;
  }
}

extern "C" void kernel_launch(void* const* d_in, const int* in_sizes, int n_in,
                              void* d_out, int out_size, void* d_ws, size_t ws_size,
                              hipStream_t stream) {
  const int*   l_ids = (const int*)d_in[0];
  const int*   r_ids = (const int*)d_in[1];
  const float* emb   = (const float*)d_in[2];
  const float* Wioux = (const float*)d_in[3];
  const float* bioux = (const float*)d_in[4];
  const float* Wiouh = (const float*)d_in[5];
  const float* biouh = (const float*)d_in[6];
  const float* Wfx   = (const float*)d_in[7];
  const float* bfx   = (const float*)d_in[8];
  const float* Wfh   = (const float*)d_in[9];
  const float* bfh   = (const float*)d_in[10];
  const float* Wh    = (const float*)d_in[11];
  const float* bh    = (const float*)d_in[12];
  const float* Wp    = (const float*)d_in[13];
  const float* bp    = (const float*)d_in[14];
  float* out = (float*)d_out;

  // workspace layout (floats): Gx [2*1024*2048], hbuf [2*512*4], hB [1024], sv [256]
  float* gx   = (float*)d_ws;
  float* hbuf = gx + (size_t)2*1024*2048;
  float* hB   = hbuf + 4096;
  float* sv   = hB + 1024;

  // zero {h,tag} buffer + hB + sv each launch (graph-captured memset node)
  hipMemsetAsync(hbuf, 0, (4096 + 1024 + 256) * sizeof(float), stream);

  gx_gemm<<<dim3(1024), dim3(256), 0, stream>>>(l_ids, r_ids, emb, Wioux, Wfx,
                                                bioux, biouh, bfx, bfh, gx);
  lstm_scan<<<dim3(64), dim3(256), 0, stream>>>(Wiouh, Wfh, gx, hbuf, hB);
  head1<<<dim3(16), dim3(256), 0, stream>>>(hbuf, hB, Wh, bh, sv);
  head2<<<dim3(1), dim3(256), 0, stream>>>(sv, Wp, bp, out);
  (void)in_sizes; (void)n_in; (void)out_size; (void)ws_size;
}

// Round 5
// 2377.644 us; speedup vs baseline: 2.0758x; 2.0758x over previous
//
#include <hip/hip_runtime.h>
#include <math.h>

#define SEQLEN 1024
#define DIM 512
#define MM 512

typedef float f32x4 __attribute__((ext_vector_type(4)));

__device__ __forceinline__ float sigf(float x) {
  return __builtin_amdgcn_rcpf(1.0f + __expf(-x));
}
__device__ __forceinline__ float tanhfast(float x) {
  return 1.0f - 2.0f * __builtin_amdgcn_rcpf(1.0f + __expf(2.0f * x));
}

// ---------------- K1: Gx[seq][t][g] = emb[ids[t]] . Wxcat[g] + bias_cat[g] ----------------
// Wxcat rows: [Wioux (1536 rows); Wfx (512 rows)], 512 cols.  Gx: [2][1024][2048]
__global__ __launch_bounds__(256) void gx_gemm(
    const int* __restrict__ l_ids, const int* __restrict__ r_ids,
    const float* __restrict__ emb,
    const float* __restrict__ Wioux, const float* __restrict__ Wfx,
    const float* __restrict__ bioux, const float* __restrict__ biouh,
    const float* __restrict__ bfx, const float* __restrict__ bfh,
    float* __restrict__ gx)
{
  __shared__ __align__(16) float At[32][68];   // transposed tiles: [k][row]
  __shared__ __align__(16) float Bt[32][68];
  const int tid = threadIdx.x;
  const int bid = blockIdx.x;
  const int seq = bid >> 9;            // 2
  const int tt  = (bid >> 5) & 15;     // 16 t-tiles of 64
  const int gt  = bid & 31;            // 32 g-tiles of 64
  const int t0 = tt * 64, g0 = gt * 64;
  const int* ids = seq ? r_ids : l_ids;

  const int li = tid >> 2;             // 0..63 (tile row)
  const int lk = (tid & 3) * 8;        // k chunk
  const float* arow = emb + (size_t)ids[t0 + li] * DIM;
  const int gg = g0 + li;
  const float* brow = (gg < 1536) ? (Wioux + (size_t)gg * DIM)
                                  : (Wfx + (size_t)(gg - 1536) * DIM);
  const int tr = tid >> 4;             // 0..15 micro-row group
  const int tc = tid & 15;             // 0..15 micro-col group

  float acc[4][4];
  #pragma unroll
  for (int i = 0; i < 4; ++i) { acc[i][0]=0.f; acc[i][1]=0.f; acc[i][2]=0.f; acc[i][3]=0.f; }

  for (int kb = 0; kb < 16; ++kb) {
    const int k0 = kb * 32;
    float4 av0 = *(const float4*)(arow + k0 + lk);
    float4 av1 = *(const float4*)(arow + k0 + lk + 4);
    float4 bv0 = *(const float4*)(brow + k0 + lk);
    float4 bv1 = *(const float4*)(brow + k0 + lk + 4);
    __syncthreads();
    At[lk+0][li]=av0.x; At[lk+1][li]=av0.y; At[lk+2][li]=av0.z; At[lk+3][li]=av0.w;
    At[lk+4][li]=av1.x; At[lk+5][li]=av1.y; At[lk+6][li]=av1.z; At[lk+7][li]=av1.w;
    Bt[lk+0][li]=bv0.x; Bt[lk+1][li]=bv0.y; Bt[lk+2][li]=bv0.z; Bt[lk+3][li]=bv0.w;
    Bt[lk+4][li]=bv1.x; Bt[lk+5][li]=bv1.y; Bt[lk+6][li]=bv1.z; Bt[lk+7][li]=bv1.w;
    __syncthreads();
    #pragma unroll
    for (int k = 0; k < 32; ++k) {
      float4 a4 = *(const float4*)&At[k][tr*4];
      float4 b4 = *(const float4*)&Bt[k][tc*4];
      acc[0][0]+=a4.x*b4.x; acc[0][1]+=a4.x*b4.y; acc[0][2]+=a4.x*b4.z; acc[0][3]+=a4.x*b4.w;
      acc[1][0]+=a4.y*b4.x; acc[1][1]+=a4.y*b4.y; acc[1][2]+=a4.y*b4.z; acc[1][3]+=a4.y*b4.w;
      acc[2][0]+=a4.z*b4.x; acc[2][1]+=a4.z*b4.y; acc[2][2]+=a4.z*b4.z; acc[2][3]+=a4.z*b4.w;
      acc[3][0]+=a4.w*b4.x; acc[3][1]+=a4.w*b4.y; acc[3][2]+=a4.w*b4.z; acc[3][3]+=a4.w*b4.w;
    }
  }
  const int gc = g0 + tc * 4;
  float badd[4];
  #pragma unroll
  for (int jj = 0; jj < 4; ++jj) {
    int g = gc + jj;
    badd[jj] = (g < 1536) ? (bioux[g] + biouh[g]) : (bfx[g-1536] + bfh[g-1536]);
  }
  #pragma unroll
  for (int ii = 0; ii < 4; ++ii) {
    float4 r;
    r.x = acc[ii][0] + badd[0];
    r.y = acc[ii][1] + badd[1];
    r.z = acc[ii][2] + badd[2];
    r.w = acc[ii][3] + badd[3];
    size_t off = ((size_t)seq * SEQLEN + (size_t)(t0 + tr*4 + ii)) * 2048 + gc;
    *(float4*)(gx + off) = r;
  }
}

// ---------------- K2: persistent scan, 64 WGs, pinned-resident weights --------------------
// hbuf: [2 parity][512 j][4] = {h_l, tag, h_r, tag}; 16B atomic coherent stores.
// Thread (jl=tid>>5, g=(tid>>4)&1, b=tid&15): gate-rows {2g,2g+1} of j=wg*8+jl,
// cols [b*32,b*32+32). Weights held in f32x4 regs, pinned via opaque asm so the
// compiler cannot re-stream them from memory each step (R3/R4 disease: VGPR=88/68).
// Exchange: each thread polls its 2 entries (32B), stages to shared LDS table,
// ONE __syncthreads, reads its 32-col chunk. Reverse WAR race closed by publish-gating.
__global__ __launch_bounds__(256, 1) void lstm_scan(
    const float* __restrict__ Wiouh, const float* __restrict__ Wfh,
    const float* __restrict__ gx,
    float* __restrict__ hbuf,       // zeroed by memset (tags start at 0)
    float* __restrict__ hB)         // [2 seq][512]
{
  const int tid  = threadIdx.x;
  const int wg   = blockIdx.x;      // 0..63
  const int b    = tid & 15;
  const int g    = (tid >> 4) & 1;
  const int jl   = tid >> 5;        // 0..7
  const int j    = wg * 8 + jl;
  const bool owner = (b == 0) && (g == 0);

  // weights: gates {2g, 2g+1} of row j (gate order i,o,u,f), cols b*32..b*32+31
  f32x4 wv0[8], wv1[8];
  {
    const int g0r = 2 * g, g1r = 2 * g + 1;
    const float* r0 = (g0r < 3) ? (Wiouh + ((size_t)g0r * 512 + j) * MM)
                                : (Wfh + (size_t)j * MM);
    const float* r1 = (g1r < 3) ? (Wiouh + ((size_t)g1r * 512 + j) * MM)
                                : (Wfh + (size_t)j * MM);
    #pragma unroll
    for (int q = 0; q < 8; ++q) {
      wv0[q] = *(const f32x4*)(r0 + b * 32 + q * 4);
      wv1[q] = *(const f32x4*)(r1 + b * 32 + q * 4);
    }
  }
  // opaque pin: values become asm outputs -> cannot be rematerialized as loads
  #pragma unroll
  for (int q = 0; q < 8; ++q) {
    asm volatile("" : "+v"(wv0[q]), "+v"(wv1[q]));
  }

  // shared h table: 16 chunks x (64 data + 4 pad) floats; chunk c holds entries
  // [c*32, c*32+32) as {hl,hr} pairs. Start banks spread over all 8 groups.
  __shared__ __align__(16) float hsm[16 * 68];

  float cl = 0.0f, cr = 0.0f;       // persistent c state (owner lanes)

  for (int t = 0; t < SEQLEN; ++t) {
    // ---- gx prefetch (owner only) — hidden under the poll ----
    float gl[4], gr[4];
    if (owner) {
      #pragma unroll
      for (int r = 0; r < 4; ++r) {
        gl[r] = gx[(size_t)t * 2048 + r * 512 + j];
        gr[r] = gx[((size_t)SEQLEN + t) * 2048 + r * 512 + j];
      }
    }

    // ---- poll own 2 entries (32B), tight spin ----
    const float* pp = hbuf + (size_t)((t & 1) * 512 + tid * 2) * 4;
    const float tf = (float)t;
    f32x4 e0, e1;
    for (;;) {
      asm volatile(
        "global_load_dwordx4 %0, %2, off sc0 sc1\n\t"
        "global_load_dwordx4 %1, %2, off offset:16 sc0 sc1\n\t"
        "s_waitcnt vmcnt(0)"
        : "=&v"(e0), "=&v"(e1)
        : "v"(pp)
        : "memory");
      if (e0[1] >= tf && e1[1] >= tf) break;
    }

    // ---- stage to shared LDS table ----
    {
      f32x4 s; s[0] = e0[0]; s[1] = e0[2]; s[2] = e1[0]; s[3] = e1[2];
      *(f32x4*)&hsm[(tid >> 4) * 68 + (tid & 15) * 4] = s;
    }
    __syncthreads();

    // ---- read own 32-col chunk: hl/hr interleaved pairs ----
    float hl[32], hr[32];
    {
      const float* rb = &hsm[b * 68];
      #pragma unroll
      for (int q = 0; q < 16; ++q) {
        f32x4 v = *(const f32x4*)(rb + q * 4);
        hl[q*2+0] = v[0]; hr[q*2+0] = v[1];
        hl[q*2+1] = v[2]; hr[q*2+1] = v[3];
      }
    }

    // ---- GEMV partials: 2 gates x 2 seqs over 32 cols ----
    float a0l = 0.f, a1l = 0.f, a0r = 0.f, a1r = 0.f;
    #pragma unroll
    for (int k = 0; k < 32; ++k) {
      const float w0k = wv0[k >> 2][k & 3];
      const float w1k = wv1[k >> 2][k & 3];
      a0l += w0k * hl[k];
      a1l += w1k * hl[k];
      a0r += w0k * hr[k];
      a1r += w1k * hr[k];
    }
    #pragma unroll
    for (int m = 1; m < 16; m <<= 1) {
      a0l += __shfl_xor(a0l, m, 64);
      a1l += __shfl_xor(a1l, m, 64);
      a0r += __shfl_xor(a0r, m, 64);
      a1r += __shfl_xor(a1r, m, 64);
    }
    // cross-g merge: g=0 lanes fetch u/f sums from g=1 partner (xor 16)
    const float b0l = __shfl_xor(a0l, 16, 64);
    const float b1l = __shfl_xor(a1l, 16, 64);
    const float b0r = __shfl_xor(a0r, 16, 64);
    const float b1r = __shfl_xor(a1r, 16, 64);

    // ---- owner: cell update + coherent 16B publish {h_l, tag, h_r, tag} ----
    if (owner) {
      const float il = a0l + gl[0], ol = a1l + gl[1], ul = b0l + gl[2], fl = b1l + gl[3];
      const float ir = a0r + gr[0], orr = a1r + gr[1], ur = b0r + gr[2], fr = b1r + gr[3];
      cl = sigf(il) * tanhfast(ul) + sigf(fl) * cl;
      cr = sigf(ir) * tanhfast(ur) + sigf(fr) * cr;
      const float h2l = sigf(ol) * tanhfast(cl);
      const float h2r = sigf(orr) * tanhfast(cr);
      const float tg = (float)(t + 1);
      f32x4 st; st[0] = h2l; st[1] = tg; st[2] = h2r; st[3] = tg;
      float* dp = hbuf + (size_t)((((t + 1) & 1) * 512 + j)) * 4;
      asm volatile("global_store_dwordx4 %0, %1, off sc0 sc1" :: "v"(dp), "v"(st) : "memory");
      if (t == SEQLEN - 1) {
        // hB = cell(x_last, 0, 0).h ; gate pre-acts are exactly gl/gr
        const float cBl = sigf(gl[0]) * tanhfast(gl[2]);
        const float cBr = sigf(gr[0]) * tanhfast(gr[2]);
        hB[j]       = sigf(gl[1]) * tanhfast(cBl);
        hB[512 + j] = sigf(gr[1]) * tanhfast(cBr);
      }
    }
  }
}

// ---------------- K3a: s = sigmoid(Wh @ vec + bh), 16 WGs x 16 rows ----------------
__global__ __launch_bounds__(256) void head1(
    const float* __restrict__ hbuf, const float* __restrict__ hB,
    const float* __restrict__ Wh, const float* __restrict__ bh,
    float* __restrict__ sv)
{
  __shared__ __align__(16) float vec[2048];
  const int tid = threadIdx.x;
  const int wg = blockIdx.x;  // 0..15
  // final h (tag 1024) lives at parity 0: entry j -> {h_l at j*4, h_r at j*4+2}
  for (int k = tid; k < 1024; k += 256) {
    float lv, rv;
    if (k < 512) { lv = hbuf[(size_t)k * 4]; rv = hbuf[(size_t)k * 4 + 2]; }
    else         { lv = hB[k - 512];         rv = hB[512 + (k - 512)]; }
    vec[k] = lv * rv;
    vec[1024 + k] = fabsf(lv - rv);
  }
  __syncthreads();
  const int row = wg * 16 + (tid >> 4);
  const int ln = tid & 15;
  const float* wr = Wh + (size_t)row * 2048 + ln * 128;
  const float* vp = vec + ln * 128;
  float acc = 0.0f;
  #pragma unroll
  for (int k = 0; k < 128; k += 4) {
    float4 wv = *(const float4*)(wr + k);
    float4 vv = *(const float4*)(vp + k);
    acc += wv.x*vv.x + wv.y*vv.y + wv.z*vv.z + wv.w*vv.w;
  }
  #pragma unroll
  for (int msk = 1; msk < 16; msk <<= 1) acc += __shfl_xor(acc, msk, 64);
  if (ln == 0) sv[row] = 1.0f / (1.0f + expf(-(acc + bh[row])));
}

// ---------------- K3b: logits = Wp @ s + bp ; log_softmax ----------------
__global__ __launch_bounds__(256) void head2(
    const float* __restrict__ sv, const float* __restrict__ Wp,
    const float* __restrict__ bp, float* __restrict__ out)
{
  __shared__ float s_l[256];
  __shared__ float lg[5];
  const int tid = threadIdx.x;
  s_l[tid] = sv[tid];
  __syncthreads();
  if (tid < 5) {
    float acc = bp[tid];
    for (int k = 0; k < 256; ++k) acc += Wp[tid*256 + k] * s_l[k];
    lg[tid] = acc;
  }
  __syncthreads();
  if (tid == 0) {
    float mx = lg[0];
    #pragma unroll
    for (int i = 1; i < 5; ++i) mx = fmaxf(mx, lg[i]);
    float sum = 0.0f;
    #pragma unroll
    for (int i = 0; i < 5; ++i) sum += expf(lg[i] - mx);
    const float lse = mx + logf(sum);
    #pragma unroll
    for (int i = 0; i < 5; ++i) out[i] = lg[i] - lse;
  }
}

extern "C" void kernel_launch(void* const* d_in, const int* in_sizes, int n_in,
                              void* d_out, int out_size, void* d_ws, size_t ws_size,
                              hipStream_t stream) {
  const int*   l_ids = (const int*)d_in[0];
  const int*   r_ids = (const int*)d_in[1];
  const float* emb   = (const float*)d_in[2];
  const float* Wioux = (const float*)d_in[3];
  const float* bioux = (const float*)d_in[4];
  const float* Wiouh = (const float*)d_in[5];
  const float* biouh = (const float*)d_in[6];
  const float* Wfx   = (const float*)d_in[7];
  const float* bfx   = (const float*)d_in[8];
  const float* Wfh   = (const float*)d_in[9];
  const float* bfh   = (const float*)d_in[10];
  const float* Wh    = (const float*)d_in[11];
  const float* bh    = (const float*)d_in[12];
  const float* Wp    = (const float*)d_in[13];
  const float* bp    = (const float*)d_in[14];
  float* out = (float*)d_out;

  // workspace layout (floats): Gx [2*1024*2048], hbuf [2*512*4], hB [1024], sv [256]
  float* gx   = (float*)d_ws;
  float* hbuf = gx + (size_t)2*1024*2048;
  float* hB   = hbuf + 4096;
  float* sv   = hB + 1024;

  // zero {h,tag} buffer + hB + sv each launch (graph-captured memset node)
  hipMemsetAsync(hbuf, 0, (4096 + 1024 + 256) * sizeof(float), stream);

  gx_gemm<<<dim3(1024), dim3(256), 0, stream>>>(l_ids, r_ids, emb, Wioux, Wfx,
                                                bioux, biouh, bfx, bfh, gx);
  lstm_scan<<<dim3(64), dim3(256), 0, stream>>>(Wiouh, Wfh, gx, hbuf, hB);
  head1<<<dim3(16), dim3(256), 0, stream>>>(hbuf, hB, Wh, bh, sv);
  head2<<<dim3(1), dim3(256), 0, stream>>>(sv, Wp, bp, out);
  (void)in_sizes; (void)n_in; (void)out_size; (void)ws_size;
}